// Round 5
// baseline (168.850 us; speedup 1.0000x reference)
//
#include <hip/hip_runtime.h>
#include <cstdint>

#define NN    1024
#define MM    32
#define NEDGE 32240
#define MROWS 64480   // 2*NEDGE
#define PX    168     // agg X tile pitch (ushorts); 336B stride -> 2-way LDS conflicts only
#define PSTN  264     // agg H pitch: 256 (H1n) + 8 pad
#define PXE   104     // edge X/LB pitch (96+8)
#define PH1   136     // edge H1 pitch (128+8)
#define PHE   72      // edge HE pitch (64+8)
#define EHALF 9984    // edge per-half LDS ushorts: Xe 3328 + H1 4352 + HE 2304 (LB overlays H1)

typedef unsigned short ushort_t;

typedef __bf16 bf16x8 __attribute__((ext_vector_type(8)));
typedef float  floatx4 __attribute__((ext_vector_type(4)));

__device__ __forceinline__ float b2f(ushort_t u) {
    union { unsigned int i; float f; } v; v.i = ((unsigned int)u) << 16; return v.f;
}
// RNE bf16 via hardware cvt (identical rounding to the old bit-trick, 1 VALU op vs 5)
__device__ __forceinline__ ushort_t f2b(float f) {
    return __builtin_bit_cast(ushort_t, (__bf16)f);
}
// K(i): number of edges before node i
__device__ __forceinline__ int edge_base(int i) {
    return (i <= MM) ? ((i * (i - 1)) >> 1) : (496 + (i - MM) * MM);
}

// ---------------- pack: weight transpose + nodes/edges bf16 ----------------
__global__ __launch_bounds__(256) void k_pack(
        const float* an1, const float* an2, const float* ae1, const float* ae2,
        const float* le1, const float* le2, const float* ln1, const float* ln2,
        const float* nodes, const float* edges,
        ushort_t* pan1, ushort_t* pan2, ushort_t* pae1, ushort_t* pae2,
        ushort_t* ple1, ushort_t* ple2, ushort_t* pln1, ushort_t* pln2,
        ushort_t* nodesb, ushort_t* edgesb) {
    __shared__ float tile[32][33];
    const int bid = blockIdx.x;
    const int tid = threadIdx.x;
    if (bid < 152) {
        const float* s; ushort_t* d; int K, N, t;
        if (bid < 40)       { s = an1; d = pan1; K = 160; N = 256; t = bid;       }
        else if (bid < 72)  { s = an2; d = pan2; K = 256; N = 128; t = bid - 40;  }
        else if (bid < 84)  { s = ae1; d = pae1; K = 96;  N = 128; t = bid - 72;  }
        else if (bid < 92)  { s = ae2; d = pae2; K = 128; N = 64;  t = bid - 84;  }
        else if (bid < 101) { s = le1; d = ple1; K = 96;  N = 96;  t = bid - 92;  }
        else if (bid < 104) { s = le2; d = ple2; K = 96;  N = 32;  t = bid - 101; }
        else if (bid < 140) { s = ln1; d = pln1; K = 192; N = 192; t = bid - 104; }
        else                { s = ln2; d = pln2; K = 192; N = 64;  t = bid - 140; }
        int ntn = N >> 5;
        int tk = t / ntn, tn = t - tk * ntn;
        int k0 = tk * 32, n0 = tn * 32;
        int tx = tid & 31, ty = tid >> 5;
#pragma unroll
        for (int m = 0; m < 4; ++m)
            tile[ty + m * 8][tx] = s[(size_t)(k0 + ty + m * 8) * N + n0 + tx];
        __syncthreads();
#pragma unroll
        for (int m = 0; m < 4; ++m)
            d[(size_t)(n0 + ty + m * 8) * K + k0 + tx] = f2b(tile[tx][ty + m * 8]);
    } else if (bid < 280) {
        int i4 = (bid - 152) * 256 + tid;
        float4 v = ((const float4*)nodes)[i4];
        uint2 o;
        o.x = (unsigned)f2b(v.x) | ((unsigned)f2b(v.y) << 16);
        o.y = (unsigned)f2b(v.z) | ((unsigned)f2b(v.w) << 16);
        ((uint2*)nodesb)[i4] = o;
    } else {
        int i4 = (bid - 280) * 256 + tid;
        if (i4 < 515840) {
            float4 v = ((const float4*)edges)[i4];
            uint2 o;
            o.x = (unsigned)f2b(v.x) | ((unsigned)f2b(v.y) << 16);
            o.y = (unsigned)f2b(v.z) | ((unsigned)f2b(v.w) << 16);
            ((uint2*)edgesb)[i4] = o;
        }
    }
}

// ---------------- main: node-centric agg (in-register window reduce -> pn) + edge branch ----------------
// Blocks 0..2047: (b,i) node blocks, 2 barriers: gather->stage1->stage2+reduce.
// Stage2 wave w owns all 32 rows x cols [16w,16w+16): window mean is per-lane masked sum
// of 8 bf16-rounded values + shfl_xor(16,32) -> pn, no LDS round-trip.
// Blocks 2048..3071: edge-pair blocks; waves 0-3 node 2q, waves 4-7 node 2q+1.
__global__ __launch_bounds__(512, 8) void k_main(
        const ushort_t* __restrict__ nodesb, const ushort_t* __restrict__ edgesb,
        const ushort_t* __restrict__ pan1, const float* __restrict__ ban1,
        const ushort_t* __restrict__ pan2, const float* __restrict__ ban2,
        const ushort_t* __restrict__ pae1, const float* __restrict__ bae1,
        const ushort_t* __restrict__ pae2, const float* __restrict__ bae2,
        const ushort_t* __restrict__ ple1, const float* __restrict__ ble1,
        const ushort_t* __restrict__ ple2, const float* __restrict__ ble2,
        ushort_t* __restrict__ pn, float* __restrict__ out_edges) {
    __shared__ alignas(16) ushort_t SH[2 * EHALF];   // 39936 B -> 4 blocks/CU
    const int tid = threadIdx.x;
    const int w = tid >> 6, l = tid & 63, lrow = l & 15, lq = l >> 4;
    const int bid = blockIdx.x;
    floatx4 zero = {0.f, 0.f, 0.f, 0.f};

    if (bid < 2048) {
        // ================= node branch =================
        const int b = bid >> 10, i = bid & 1023;
        const int t = min(i, MM);
        if (i == 0) {                     // pn row 0 = zeros (block-uniform, before any barrier)
            if (tid < 64) ((unsigned*)(pn + (size_t)bid * 128))[tid] = 0u;
            return;
        }
        const int j0 = i - t;
        const int base = b * NEDGE + edge_base(i);
        ushort_t* X = SH;                 // 32*PX gather tile
        ushort_t* H = SH + 32 * PX;       // 32*PSTN H1n tile

        // stage-1 B fragments (issued before gather for latency overlap)
        bf16x8 B0[5], B1[5];
#pragma unroll
        for (int kt = 0; kt < 5; ++kt) {
            B0[kt] = *(const bf16x8*)(pan1 + (size_t)(16 * w + lrow) * 160 + kt * 32 + lq * 8);
            B1[kt] = *(const bf16x8*)(pan1 + (size_t)(16 * (w + 8) + lrow) * 160 + kt * 32 + lq * 8);
        }
        float c0 = ban1[16 * w + lrow];
        float c1 = ban1[16 * (w + 8) + lrow];

        // analytic gather: row rr -> [node j0+rr | edge base+rr | node i]
#pragma unroll
        for (int k = 0; k < 4; ++k) {
            int rr = w * 4 + k;
            unsigned* xr = (unsigned*)(X + rr * PX);
            const unsigned* nj = (const unsigned*)(nodesb + (size_t)(b * NN + j0 + rr) * 64);
            const unsigned* ni = (const unsigned*)(nodesb + (size_t)(b * NN + i) * 64);
            const unsigned* eb = (const unsigned*)(edgesb + (size_t)(base + rr) * 32);
            if (l < 32) { xr[l] = nj[l]; xr[48 + l] = ni[l]; }
            else        xr[l] = eb[l - 32];
        }
        __syncthreads();   // A: X ready

        // stage 1: an1 160->256, wave w -> col-tiles {w, w+8}
#pragma unroll
        for (int s = 0; s < 2; ++s) {
            bf16x8 A[5];
#pragma unroll
            for (int kt = 0; kt < 5; ++kt)
                A[kt] = *(const bf16x8*)&X[(s * 16 + lrow) * PX + kt * 32 + lq * 8];
            floatx4 a0 = zero, a1 = zero;
#pragma unroll
            for (int kt = 0; kt < 5; ++kt) {
                a0 = __builtin_amdgcn_mfma_f32_16x16x32_bf16(A[kt], B0[kt], a0, 0, 0, 0);
                a1 = __builtin_amdgcn_mfma_f32_16x16x32_bf16(A[kt], B1[kt], a1, 0, 0, 0);
            }
#pragma unroll
            for (int r_ = 0; r_ < 4; ++r_) {
                int row = (s * 16 + lq * 4 + r_) * PSTN;
                H[row + 16 * w + lrow]       = f2b(fmaxf(a0[r_] + c0, 0.f));
                H[row + 128 + 16 * w + lrow] = f2b(fmaxf(a1[r_] + c1, 0.f));
            }
        }
        __syncthreads();   // B: H ready

        // stage 2 + in-register window mean -> pn[b,i]
        {
            bf16x8 D[8];
#pragma unroll
            for (int kt = 0; kt < 8; ++kt)
                D[kt] = *(const bf16x8*)(pan2 + (size_t)(16 * w + lrow) * 256 + kt * 32 + lq * 8);
            float d0 = ban2[16 * w + lrow];
            float P = 0.f;
#pragma unroll
            for (int s = 0; s < 2; ++s) {
                floatx4 a0 = zero;
#pragma unroll
                for (int kt = 0; kt < 8; ++kt) {
                    bf16x8 a = *(const bf16x8*)&H[(s * 16 + lrow) * PSTN + kt * 32 + lq * 8];
                    a0 = __builtin_amdgcn_mfma_f32_16x16x32_bf16(a, D[kt], a0, 0, 0, 0);
                }
#pragma unroll
                for (int r_ = 0; r_ < 4; ++r_) {
                    int row = s * 16 + lq * 4 + r_;
                    float v = fmaxf(a0[r_] + d0, 0.f);
                    float vr = b2f(f2b(v));            // bf16-rounded, same values k_mid summed
                    if (row < t) P += vr;
                }
            }
            P += __shfl_xor(P, 16);
            P += __shfl_xor(P, 32);
            if (l < 16)
                pn[(size_t)bid * 128 + 16 * w + lrow] = f2b(P * (1.0f / (float)t));
        }
    } else {
        // ================= edge branch: 2 nodes/block, one per 4-wave half =================
        const int q = bid - 2048;
        const int h = w >> 2, w4 = w & 3;        // half, wave-within-half
        const int lt = tid & 255;                // thread-within-half
        const int ri = 2 * q + h;
        const int b = ri >> 10, i = ri & 1023;
        const int t = min(i, MM);                // t==0 half: runs through, stores guarded out
        const int j0 = i - t;
        const int base = b * NEDGE + edge_base(i);
        ushort_t* Xe = SH + h * EHALF;           // [node_j(64) | edge(32)]; cols 0..63 -> pre
        ushort_t* H1 = Xe + 3328;                // ae1 output (128)
        ushort_t* HE = H1 + 4352;                // he (64)
        ushort_t* LB = H1;                       // le1 output (96) overlays H1 (dead after B3)

        // ae1 B fragments early (overlap with gather)
        bf16x8 B0[3], B1[3];
#pragma unroll
        for (int kt = 0; kt < 3; ++kt) {
            B0[kt] = *(const bf16x8*)(pae1 + (size_t)(16 * w4 + lrow) * 96 + kt * 32 + lq * 8);
            B1[kt] = *(const bf16x8*)(pae1 + (size_t)(16 * (w4 + 4) + lrow) * 96 + kt * 32 + lq * 8);
        }
        const float c0 = bae1[16 * w4 + lrow];
        const float c1 = bae1[16 * (w4 + 4) + lrow];

        // gather 32 rows x [node_j(32u) | edge(16u)]  (rows >= t read valid memory; discarded)
        for (int u = lt; u < 32 * 48; u += 256) {
            int row = u / 48, c = u - row * 48;
            unsigned v;
            if (c < 32) v = ((const unsigned*)nodesb)[(size_t)(b * NN + j0 + row) * 32 + c];
            else        v = ((const unsigned*)edgesb)[(size_t)(base + row) * 16 + (c - 32)];
            ((unsigned*)Xe)[row * (PXE / 2) + c] = v;
        }
        __syncthreads();   // B1: both halves' X ready

        // he stage 1: ae1 96->128, wave w4 -> col-tiles {w4, w4+4}
#pragma unroll
        for (int s = 0; s < 2; ++s) {
            bf16x8 A[3];
#pragma unroll
            for (int kt = 0; kt < 3; ++kt)
                A[kt] = *(const bf16x8*)&Xe[(s * 16 + lrow) * PXE + kt * 32 + lq * 8];
            floatx4 a0 = zero, a1 = zero;
#pragma unroll
            for (int kt = 0; kt < 3; ++kt) {
                a0 = __builtin_amdgcn_mfma_f32_16x16x32_bf16(A[kt], B0[kt], a0, 0, 0, 0);
                a1 = __builtin_amdgcn_mfma_f32_16x16x32_bf16(A[kt], B1[kt], a1, 0, 0, 0);
            }
#pragma unroll
            for (int r_ = 0; r_ < 4; ++r_) {
                int row = (s * 16 + lq * 4 + r_) * PH1;
                H1[row + 16 * w4 + lrow]      = f2b(fmaxf(a0[r_] + c0, 0.f));
                H1[row + 64 + 16 * w4 + lrow] = f2b(fmaxf(a1[r_] + c1, 0.f));
            }
        }
        __syncthreads();   // B2: H1 ready

        // he stage 2: ae2 128->64, wave w4 -> col-tile w4 (own 16 HE cols)
        {
            bf16x8 E[4];
#pragma unroll
            for (int kt = 0; kt < 4; ++kt)
                E[kt] = *(const bf16x8*)(pae2 + (size_t)(16 * w4 + lrow) * 128 + kt * 32 + lq * 8);
            float d2 = bae2[16 * w4 + lrow];
#pragma unroll
            for (int s = 0; s < 2; ++s) {
                floatx4 a2 = zero;
#pragma unroll
                for (int kt = 0; kt < 4; ++kt) {
                    bf16x8 a = *(const bf16x8*)&H1[(s * 16 + lrow) * PH1 + kt * 32 + lq * 8];
                    a2 = __builtin_amdgcn_mfma_f32_16x16x32_bf16(a, E[kt], a2, 0, 0, 0);
                }
#pragma unroll
                for (int r_ = 0; r_ < 4; ++r_)
                    HE[(s * 16 + lq * 4 + r_) * PHE + 16 * w4 + lrow] = f2b(fmaxf(a2[r_] + d2, 0.f));
            }
        }
        // prefix-mean over this wave's own 16 HE cols (same-wave LDS RAW; no barrier needed)
        if (l < 16) {
            float run = 0.f;
            for (int p = 0; p < t; ++p) {
                Xe[p * PXE + 16 * w4 + l] = f2b((p == 0) ? 0.f : run / (float)p);
                run += b2f(HE[p * PHE + 16 * w4 + l]);
            }
        }
        __syncthreads();   // B3: pre (Xe cols 0..63) ready; H1 reads complete -> LB may reuse it

        // le1: 96->96, 6 col-tiles: wave w4 -> tile w4; waves 0,1 also -> tiles 4,5
        {
            bf16x8 F0[3], F1[3];
            const bool two = (w4 < 2);
#pragma unroll
            for (int kt = 0; kt < 3; ++kt) {
                F0[kt] = *(const bf16x8*)(ple1 + (size_t)(16 * w4 + lrow) * 96 + kt * 32 + lq * 8);
                if (two)
                    F1[kt] = *(const bf16x8*)(ple1 + (size_t)(16 * (w4 + 4) + lrow) * 96 + kt * 32 + lq * 8);
            }
            float v0 = ble1[16 * w4 + lrow];
            float v1 = two ? ble1[16 * (w4 + 4) + lrow] : 0.f;
#pragma unroll
            for (int s = 0; s < 2; ++s) {
                bf16x8 A[3];
#pragma unroll
                for (int kt = 0; kt < 3; ++kt)
                    A[kt] = *(const bf16x8*)&Xe[(s * 16 + lrow) * PXE + kt * 32 + lq * 8];
                floatx4 a0 = zero, a1 = zero;
#pragma unroll
                for (int kt = 0; kt < 3; ++kt) {
                    a0 = __builtin_amdgcn_mfma_f32_16x16x32_bf16(A[kt], F0[kt], a0, 0, 0, 0);
                    if (two)
                        a1 = __builtin_amdgcn_mfma_f32_16x16x32_bf16(A[kt], F1[kt], a1, 0, 0, 0);
                }
#pragma unroll
                for (int r_ = 0; r_ < 4; ++r_) {
                    int row = (s * 16 + lq * 4 + r_) * PXE;
                    LB[row + 16 * w4 + lrow] = f2b(fmaxf(a0[r_] + v0, 0.f));
                    if (two)
                        LB[row + 64 + 16 * w4 + lrow] = f2b(fmaxf(a1[r_] + v1, 0.f));
                }
            }
        }
        __syncthreads();   // B4: LB ready

        // le2: 96->32, wave w4 -> col-tile (w4&1), row-subtile (w4>>1); stores guarded rows < t
        {
            int ct = w4 & 1, s = w4 >> 1;
            int c0o = 16 * ct;
            bf16x8 F2[3];
#pragma unroll
            for (int kt = 0; kt < 3; ++kt)
                F2[kt] = *(const bf16x8*)(ple2 + (size_t)(c0o + lrow) * 96 + kt * 32 + lq * 8);
            float v2 = ble2[c0o + lrow];
            floatx4 a2 = zero;
#pragma unroll
            for (int kt = 0; kt < 3; ++kt) {
                bf16x8 a = *(const bf16x8*)&LB[(s * 16 + lrow) * PXE + kt * 32 + lq * 8];
                a2 = __builtin_amdgcn_mfma_f32_16x16x32_bf16(a, F2[kt], a2, 0, 0, 0);
            }
#pragma unroll
            for (int r_ = 0; r_ < 4; ++r_) {
                int grow = s * 16 + lq * 4 + r_;
                if (grow < t)
                    out_edges[(size_t)(base + grow) * 32 + c0o + lrow] = fmaxf(a2[r_] + v2, 0.f);
            }
        }
    }
}

// ---------------- final: node MLP ([pn|nodesb] 192->192->64) ----------------
__global__ __launch_bounds__(192) void k_final(
        const ushort_t* __restrict__ pn, const ushort_t* __restrict__ nodesb,
        const ushort_t* __restrict__ pln1, const float* __restrict__ bln1,
        const ushort_t* __restrict__ pln2, const float* __restrict__ bln2,
        float* __restrict__ out_nodes) {
    __shared__ alignas(16) ushort_t LA[32 * 200];
    __shared__ alignas(16) ushort_t LB[32 * 200];
    const int tid = threadIdx.x;
    const int w = tid >> 6, l = tid & 63, lrow = l & 15, lq = l >> 4;
    floatx4 zero = {0.f, 0.f, 0.f, 0.f};

    int tile = blockIdx.x;
    for (int u = tid; u < 768; u += 192) {        // 32 rows x 24 uint4 chunks
        int row = u / 24, c = u - row * 24;
        int r = tile * 32 + row;
        const uint4* src = (c < 16) ? ((const uint4*)(pn + (size_t)r * 128) + c)
                                    : ((const uint4*)(nodesb + (size_t)r * 64) + (c - 16));
        *(uint4*)&LA[row * 200 + c * 8] = *src;
    }
    bf16x8 f1[6][4]; float v1[4];
#pragma unroll
    for (int kt = 0; kt < 6; ++kt)
#pragma unroll
        for (int nt = 0; nt < 4; ++nt)
            f1[kt][nt] = *(const bf16x8*)(pln1 + (size_t)(w * 64 + nt * 16 + lrow) * 192 + kt * 32 + lq * 8);
#pragma unroll
    for (int nt = 0; nt < 4; ++nt) v1[nt] = bln1[w * 64 + nt * 16 + lrow];
    __syncthreads();

    floatx4 acc[2][4];
#pragma unroll
    for (int s = 0; s < 2; ++s)
#pragma unroll
        for (int nt = 0; nt < 4; ++nt) acc[s][nt] = zero;
#pragma unroll
    for (int s = 0; s < 2; ++s)
#pragma unroll
        for (int kt = 0; kt < 6; ++kt) {
            bf16x8 a = *(const bf16x8*)&LA[(s * 16 + lrow) * 200 + kt * 32 + lq * 8];
#pragma unroll
            for (int nt = 0; nt < 4; ++nt)
                acc[s][nt] = __builtin_amdgcn_mfma_f32_16x16x32_bf16(a, f1[kt][nt], acc[s][nt], 0, 0, 0);
        }
#pragma unroll
    for (int s = 0; s < 2; ++s)
#pragma unroll
        for (int nt = 0; nt < 4; ++nt) {
            int col = w * 64 + nt * 16 + lrow;
#pragma unroll
            for (int r_ = 0; r_ < 4; ++r_)
                LB[(s * 16 + lq * 4 + r_) * 200 + col] = f2b(fmaxf(acc[s][nt][r_] + v1[nt], 0.f));
        }
    bf16x8 f2[6][2]; float v2[2] = {0.f, 0.f};
    if (w < 2) {
#pragma unroll
        for (int kt = 0; kt < 6; ++kt)
#pragma unroll
            for (int nt = 0; nt < 2; ++nt)
                f2[kt][nt] = *(const bf16x8*)(pln2 + (size_t)(w * 32 + nt * 16 + lrow) * 192 + kt * 32 + lq * 8);
#pragma unroll
        for (int nt = 0; nt < 2; ++nt) v2[nt] = bln2[w * 32 + nt * 16 + lrow];
    }
    __syncthreads();
    if (w < 2) {
        floatx4 a2[2][2];
#pragma unroll
        for (int s = 0; s < 2; ++s) { a2[s][0] = zero; a2[s][1] = zero; }
#pragma unroll
        for (int s = 0; s < 2; ++s)
#pragma unroll
            for (int kt = 0; kt < 6; ++kt) {
                bf16x8 a = *(const bf16x8*)&LB[(s * 16 + lrow) * 200 + kt * 32 + lq * 8];
#pragma unroll
                for (int nt = 0; nt < 2; ++nt)
                    a2[s][nt] = __builtin_amdgcn_mfma_f32_16x16x32_bf16(a, f2[kt][nt], a2[s][nt], 0, 0, 0);
            }
#pragma unroll
        for (int s = 0; s < 2; ++s)
#pragma unroll
            for (int nt = 0; nt < 2; ++nt) {
                int col = w * 32 + nt * 16 + lrow;
#pragma unroll
                for (int r_ = 0; r_ < 4; ++r_)
                    out_nodes[(size_t)(tile * 32 + s * 16 + lq * 4 + r_) * 64 + col] =
                        fmaxf(a2[s][nt][r_] + v2[nt], 0.f);
            }
    }
}

extern "C" void kernel_launch(void* const* d_in, const int* in_sizes, int n_in,
                              void* d_out, int out_size, void* d_ws, size_t ws_size,
                              hipStream_t stream) {
    const float* nodes = (const float*)d_in[0];
    const float* edges = (const float*)d_in[1];
    const float* Wan1 = (const float*)d_in[2];  const float* ban1 = (const float*)d_in[3];
    const float* Wan2 = (const float*)d_in[4];  const float* ban2 = (const float*)d_in[5];
    const float* Wln1 = (const float*)d_in[6];  const float* bln1 = (const float*)d_in[7];
    const float* Wln2 = (const float*)d_in[8];  const float* bln2 = (const float*)d_in[9];
    const float* Wae1 = (const float*)d_in[10]; const float* bae1 = (const float*)d_in[11];
    const float* Wae2 = (const float*)d_in[12]; const float* bae2 = (const float*)d_in[13];
    const float* Wle1 = (const float*)d_in[14]; const float* ble1 = (const float*)d_in[15];
    const float* Wle2 = (const float*)d_in[16]; const float* ble2 = (const float*)d_in[17];

    char* ws = (char*)d_ws;
    size_t o = 0;
    auto alloc = [&](size_t bytes) -> void* {
        void* r = ws + o;
        o += (bytes + 255) & ~(size_t)255;
        return r;
    };
    ushort_t* pn     = (ushort_t*)alloc((size_t)2048 * 128 * 2);
    ushort_t* nodesb = (ushort_t*)alloc((size_t)2 * NN * 64 * 2);
    ushort_t* edgesb = (ushort_t*)alloc((size_t)MROWS * 32 * 2);
    ushort_t* pan1 = (ushort_t*)alloc(160 * 256 * 2);
    ushort_t* pan2 = (ushort_t*)alloc(256 * 128 * 2);
    ushort_t* pae1 = (ushort_t*)alloc(96 * 128 * 2);
    ushort_t* pae2 = (ushort_t*)alloc(128 * 64 * 2);
    ushort_t* ple1 = (ushort_t*)alloc(96 * 96 * 2);
    ushort_t* ple2 = (ushort_t*)alloc(96 * 32 * 2);
    ushort_t* pln1 = (ushort_t*)alloc(192 * 192 * 2);
    ushort_t* pln2 = (ushort_t*)alloc(192 * 64 * 2);

    float* out_nodes = (float*)d_out;
    float* out_edges = (float*)d_out + 2 * NN * 64;

    k_pack<<<2296, 256, 0, stream>>>(Wan1, Wan2, Wae1, Wae2, Wle1, Wle2, Wln1, Wln2,
                                     nodes, edges,
                                     pan1, pan2, pae1, pae2, ple1, ple2, pln1, pln2,
                                     nodesb, edgesb);
    k_main<<<3072, 512, 0, stream>>>(nodesb, edgesb,
                                     pan1, ban1, pan2, ban2,
                                     pae1, bae1, pae2, bae2,
                                     ple1, ble1, ple2, ble2,
                                     pn, out_edges);
    k_final<<<64, 192, 0, stream>>>(pn, nodesb, pln1, bln1, pln2, bln2, out_nodes);

    (void)in_sizes; (void)n_in; (void)out_size; (void)ws_size;
}

// Round 6
// 154.852 us; speedup vs baseline: 1.0904x; 1.0904x over previous
//
#include <hip/hip_runtime.h>
#include <cstdint>

#define NN    1024
#define MM    32
#define NEDGE 32240
#define MROWS 64480   // 2*NEDGE
#define PX    168     // agg X tile pitch (ushorts); 336B stride -> 2-way LDS conflicts only
#define PSTN  264     // agg H pitch: 256 (H1n) + 8 pad
#define PXE   104     // edge X/LB pitch (96+8)
#define PH1   136     // edge H1 pitch (128+8)
#define PHE   72      // edge HE pitch (64+8)
#define EHALF 9984    // edge per-half LDS ushorts: Xe 3328 + H1 4352 + HE 2304 (LB overlays H1)

typedef unsigned short ushort_t;

typedef __bf16 bf16x8 __attribute__((ext_vector_type(8)));
typedef float  floatx4 __attribute__((ext_vector_type(4)));

__device__ __forceinline__ float b2f(ushort_t u) {
    union { unsigned int i; float f; } v; v.i = ((unsigned int)u) << 16; return v.f;
}
// RNE bf16 via hardware cvt (identical rounding to the old bit-trick, 1 VALU op vs 5)
__device__ __forceinline__ ushort_t f2b(float f) {
    return __builtin_bit_cast(ushort_t, (__bf16)f);
}
// K(i): number of edges before node i
__device__ __forceinline__ int edge_base(int i) {
    return (i <= MM) ? ((i * (i - 1)) >> 1) : (496 + (i - MM) * MM);
}

// ---------------- pack: weight transpose + nodes/edges bf16 ----------------
__global__ __launch_bounds__(256) void k_pack(
        const float* an1, const float* an2, const float* ae1, const float* ae2,
        const float* le1, const float* le2, const float* ln1, const float* ln2,
        const float* nodes, const float* edges,
        ushort_t* pan1, ushort_t* pan2, ushort_t* pae1, ushort_t* pae2,
        ushort_t* ple1, ushort_t* ple2, ushort_t* pln1, ushort_t* pln2,
        ushort_t* nodesb, ushort_t* edgesb) {
    __shared__ float tile[32][33];
    const int bid = blockIdx.x;
    const int tid = threadIdx.x;
    if (bid < 152) {
        const float* s; ushort_t* d; int K, N, t;
        if (bid < 40)       { s = an1; d = pan1; K = 160; N = 256; t = bid;       }
        else if (bid < 72)  { s = an2; d = pan2; K = 256; N = 128; t = bid - 40;  }
        else if (bid < 84)  { s = ae1; d = pae1; K = 96;  N = 128; t = bid - 72;  }
        else if (bid < 92)  { s = ae2; d = pae2; K = 128; N = 64;  t = bid - 84;  }
        else if (bid < 101) { s = le1; d = ple1; K = 96;  N = 96;  t = bid - 92;  }
        else if (bid < 104) { s = le2; d = ple2; K = 96;  N = 32;  t = bid - 101; }
        else if (bid < 140) { s = ln1; d = pln1; K = 192; N = 192; t = bid - 104; }
        else                { s = ln2; d = pln2; K = 192; N = 64;  t = bid - 140; }
        int ntn = N >> 5;
        int tk = t / ntn, tn = t - tk * ntn;
        int k0 = tk * 32, n0 = tn * 32;
        int tx = tid & 31, ty = tid >> 5;
#pragma unroll
        for (int m = 0; m < 4; ++m)
            tile[ty + m * 8][tx] = s[(size_t)(k0 + ty + m * 8) * N + n0 + tx];
        __syncthreads();
#pragma unroll
        for (int m = 0; m < 4; ++m)
            d[(size_t)(n0 + ty + m * 8) * K + k0 + tx] = f2b(tile[tx][ty + m * 8]);
    } else if (bid < 280) {
        int i4 = (bid - 152) * 256 + tid;
        float4 v = ((const float4*)nodes)[i4];
        uint2 o;
        o.x = (unsigned)f2b(v.x) | ((unsigned)f2b(v.y) << 16);
        o.y = (unsigned)f2b(v.z) | ((unsigned)f2b(v.w) << 16);
        ((uint2*)nodesb)[i4] = o;
    } else {
        int i4 = (bid - 280) * 256 + tid;
        if (i4 < 515840) {
            float4 v = ((const float4*)edges)[i4];
            uint2 o;
            o.x = (unsigned)f2b(v.x) | ((unsigned)f2b(v.y) << 16);
            o.y = (unsigned)f2b(v.z) | ((unsigned)f2b(v.w) << 16);
            ((uint2*)edgesb)[i4] = o;
        }
    }
}

// ---------------- main: node-centric agg (in-register window reduce -> pn) + edge branch ----------------
// Blocks 0..2047: (b,i) node blocks, 2 barriers: gather->stage1->stage2+reduce.
// Stage2 wave w owns all 32 rows x cols [16w,16w+16): window mean is per-lane masked sum
// of 8 bf16-rounded values + shfl_xor(16,32) -> pn, no LDS round-trip.
// Blocks 2048..3071: edge-pair blocks; waves 0-3 node 2q, waves 4-7 node 2q+1.
// launch_bounds min-waves=4 (NOT 8): 8 forced VGPR=32 -> scratch spill, FETCH 26MB/WRITE 74MB (round-5 regression).
__global__ __launch_bounds__(512, 4) void k_main(
        const ushort_t* __restrict__ nodesb, const ushort_t* __restrict__ edgesb,
        const ushort_t* __restrict__ pan1, const float* __restrict__ ban1,
        const ushort_t* __restrict__ pan2, const float* __restrict__ ban2,
        const ushort_t* __restrict__ pae1, const float* __restrict__ bae1,
        const ushort_t* __restrict__ pae2, const float* __restrict__ bae2,
        const ushort_t* __restrict__ ple1, const float* __restrict__ ble1,
        const ushort_t* __restrict__ ple2, const float* __restrict__ ble2,
        ushort_t* __restrict__ pn, float* __restrict__ out_edges) {
    __shared__ alignas(16) ushort_t SH[2 * EHALF];   // 39936 B -> 4 blocks/CU LDS-wise
    const int tid = threadIdx.x;
    const int w = tid >> 6, l = tid & 63, lrow = l & 15, lq = l >> 4;
    const int bid = blockIdx.x;
    floatx4 zero = {0.f, 0.f, 0.f, 0.f};

    if (bid < 2048) {
        // ================= node branch =================
        const int b = bid >> 10, i = bid & 1023;
        const int t = min(i, MM);
        if (i == 0) {                     // pn row 0 = zeros (block-uniform, before any barrier)
            if (tid < 64) ((unsigned*)(pn + (size_t)bid * 128))[tid] = 0u;
            return;
        }
        const int j0 = i - t;
        const int base = b * NEDGE + edge_base(i);
        ushort_t* X = SH;                 // 32*PX gather tile
        ushort_t* H = SH + 32 * PX;       // 32*PSTN H1n tile

        // stage-1 B fragments (issued before gather for latency overlap)
        bf16x8 B0[5], B1[5];
#pragma unroll
        for (int kt = 0; kt < 5; ++kt) {
            B0[kt] = *(const bf16x8*)(pan1 + (size_t)(16 * w + lrow) * 160 + kt * 32 + lq * 8);
            B1[kt] = *(const bf16x8*)(pan1 + (size_t)(16 * (w + 8) + lrow) * 160 + kt * 32 + lq * 8);
        }
        float c0 = ban1[16 * w + lrow];
        float c1 = ban1[16 * (w + 8) + lrow];

        // analytic gather: row rr -> [node j0+rr | edge base+rr | node i]
#pragma unroll
        for (int k = 0; k < 4; ++k) {
            int rr = w * 4 + k;
            unsigned* xr = (unsigned*)(X + rr * PX);
            const unsigned* nj = (const unsigned*)(nodesb + (size_t)(b * NN + j0 + rr) * 64);
            const unsigned* ni = (const unsigned*)(nodesb + (size_t)(b * NN + i) * 64);
            const unsigned* eb = (const unsigned*)(edgesb + (size_t)(base + rr) * 32);
            if (l < 32) { xr[l] = nj[l]; xr[48 + l] = ni[l]; }
            else        xr[l] = eb[l - 32];
        }
        __syncthreads();   // A: X ready

        // stage 1: an1 160->256, wave w -> col-tiles {w, w+8}
#pragma unroll
        for (int s = 0; s < 2; ++s) {
            bf16x8 A[5];
#pragma unroll
            for (int kt = 0; kt < 5; ++kt)
                A[kt] = *(const bf16x8*)&X[(s * 16 + lrow) * PX + kt * 32 + lq * 8];
            floatx4 a0 = zero, a1 = zero;
#pragma unroll
            for (int kt = 0; kt < 5; ++kt) {
                a0 = __builtin_amdgcn_mfma_f32_16x16x32_bf16(A[kt], B0[kt], a0, 0, 0, 0);
                a1 = __builtin_amdgcn_mfma_f32_16x16x32_bf16(A[kt], B1[kt], a1, 0, 0, 0);
            }
#pragma unroll
            for (int r_ = 0; r_ < 4; ++r_) {
                int row = (s * 16 + lq * 4 + r_) * PSTN;
                H[row + 16 * w + lrow]       = f2b(fmaxf(a0[r_] + c0, 0.f));
                H[row + 128 + 16 * w + lrow] = f2b(fmaxf(a1[r_] + c1, 0.f));
            }
        }
        __syncthreads();   // B: H ready

        // stage 2 + in-register window mean -> pn[b,i]
        {
            bf16x8 D[8];
#pragma unroll
            for (int kt = 0; kt < 8; ++kt)
                D[kt] = *(const bf16x8*)(pan2 + (size_t)(16 * w + lrow) * 256 + kt * 32 + lq * 8);
            float d0 = ban2[16 * w + lrow];
            float P = 0.f;
#pragma unroll
            for (int s = 0; s < 2; ++s) {
                floatx4 a0 = zero;
#pragma unroll
                for (int kt = 0; kt < 8; ++kt) {
                    bf16x8 a = *(const bf16x8*)&H[(s * 16 + lrow) * PSTN + kt * 32 + lq * 8];
                    a0 = __builtin_amdgcn_mfma_f32_16x16x32_bf16(a, D[kt], a0, 0, 0, 0);
                }
#pragma unroll
                for (int r_ = 0; r_ < 4; ++r_) {
                    int row = s * 16 + lq * 4 + r_;
                    float v = fmaxf(a0[r_] + d0, 0.f);
                    float vr = b2f(f2b(v));            // bf16-rounded, same values k_mid summed
                    if (row < t) P += vr;
                }
            }
            P += __shfl_xor(P, 16);
            P += __shfl_xor(P, 32);
            if (l < 16)
                pn[(size_t)bid * 128 + 16 * w + lrow] = f2b(P * (1.0f / (float)t));
        }
    } else {
        // ================= edge branch: 2 nodes/block, one per 4-wave half =================
        const int q = bid - 2048;
        const int h = w >> 2, w4 = w & 3;        // half, wave-within-half
        const int lt = tid & 255;                // thread-within-half
        const int ri = 2 * q + h;
        const int b = ri >> 10, i = ri & 1023;
        const int t = min(i, MM);                // t==0 half: runs through, stores guarded out
        const int j0 = i - t;
        const int base = b * NEDGE + edge_base(i);
        ushort_t* Xe = SH + h * EHALF;           // [node_j(64) | edge(32)]; cols 0..63 -> pre
        ushort_t* H1 = Xe + 3328;                // ae1 output (128)
        ushort_t* HE = H1 + 4352;                // he (64)
        ushort_t* LB = H1;                       // le1 output (96) overlays H1 (dead after B3)

        // ae1 B fragments early (overlap with gather)
        bf16x8 B0[3], B1[3];
#pragma unroll
        for (int kt = 0; kt < 3; ++kt) {
            B0[kt] = *(const bf16x8*)(pae1 + (size_t)(16 * w4 + lrow) * 96 + kt * 32 + lq * 8);
            B1[kt] = *(const bf16x8*)(pae1 + (size_t)(16 * (w4 + 4) + lrow) * 96 + kt * 32 + lq * 8);
        }
        const float c0 = bae1[16 * w4 + lrow];
        const float c1 = bae1[16 * (w4 + 4) + lrow];

        // gather 32 rows x [node_j(32u) | edge(16u)]  (rows >= t read valid memory; discarded)
        for (int u = lt; u < 32 * 48; u += 256) {
            int row = u / 48, c = u - row * 48;
            unsigned v;
            if (c < 32) v = ((const unsigned*)nodesb)[(size_t)(b * NN + j0 + row) * 32 + c];
            else        v = ((const unsigned*)edgesb)[(size_t)(base + row) * 16 + (c - 32)];
            ((unsigned*)Xe)[row * (PXE / 2) + c] = v;
        }
        __syncthreads();   // B1: both halves' X ready

        // he stage 1: ae1 96->128, wave w4 -> col-tiles {w4, w4+4}
#pragma unroll
        for (int s = 0; s < 2; ++s) {
            bf16x8 A[3];
#pragma unroll
            for (int kt = 0; kt < 3; ++kt)
                A[kt] = *(const bf16x8*)&Xe[(s * 16 + lrow) * PXE + kt * 32 + lq * 8];
            floatx4 a0 = zero, a1 = zero;
#pragma unroll
            for (int kt = 0; kt < 3; ++kt) {
                a0 = __builtin_amdgcn_mfma_f32_16x16x32_bf16(A[kt], B0[kt], a0, 0, 0, 0);
                a1 = __builtin_amdgcn_mfma_f32_16x16x32_bf16(A[kt], B1[kt], a1, 0, 0, 0);
            }
#pragma unroll
            for (int r_ = 0; r_ < 4; ++r_) {
                int row = (s * 16 + lq * 4 + r_) * PH1;
                H1[row + 16 * w4 + lrow]      = f2b(fmaxf(a0[r_] + c0, 0.f));
                H1[row + 64 + 16 * w4 + lrow] = f2b(fmaxf(a1[r_] + c1, 0.f));
            }
        }
        __syncthreads();   // B2: H1 ready

        // he stage 2: ae2 128->64, wave w4 -> col-tile w4 (own 16 HE cols)
        {
            bf16x8 E[4];
#pragma unroll
            for (int kt = 0; kt < 4; ++kt)
                E[kt] = *(const bf16x8*)(pae2 + (size_t)(16 * w4 + lrow) * 128 + kt * 32 + lq * 8);
            float d2 = bae2[16 * w4 + lrow];
#pragma unroll
            for (int s = 0; s < 2; ++s) {
                floatx4 a2 = zero;
#pragma unroll
                for (int kt = 0; kt < 4; ++kt) {
                    bf16x8 a = *(const bf16x8*)&H1[(s * 16 + lrow) * PH1 + kt * 32 + lq * 8];
                    a2 = __builtin_amdgcn_mfma_f32_16x16x32_bf16(a, E[kt], a2, 0, 0, 0);
                }
#pragma unroll
                for (int r_ = 0; r_ < 4; ++r_)
                    HE[(s * 16 + lq * 4 + r_) * PHE + 16 * w4 + lrow] = f2b(fmaxf(a2[r_] + d2, 0.f));
            }
        }
        // prefix-mean over this wave's own 16 HE cols (same-wave LDS RAW; no barrier needed)
        if (l < 16) {
            float run = 0.f;
            for (int p = 0; p < t; ++p) {
                Xe[p * PXE + 16 * w4 + l] = f2b((p == 0) ? 0.f : run / (float)p);
                run += b2f(HE[p * PHE + 16 * w4 + l]);
            }
        }
        __syncthreads();   // B3: pre (Xe cols 0..63) ready; H1 reads complete -> LB may reuse it

        // le1: 96->96, 6 col-tiles: wave w4 -> tile w4; waves 0,1 also -> tiles 4,5
        {
            bf16x8 F0[3], F1[3];
            const bool two = (w4 < 2);
#pragma unroll
            for (int kt = 0; kt < 3; ++kt) {
                F0[kt] = *(const bf16x8*)(ple1 + (size_t)(16 * w4 + lrow) * 96 + kt * 32 + lq * 8);
                if (two)
                    F1[kt] = *(const bf16x8*)(ple1 + (size_t)(16 * (w4 + 4) + lrow) * 96 + kt * 32 + lq * 8);
            }
            float v0 = ble1[16 * w4 + lrow];
            float v1 = two ? ble1[16 * (w4 + 4) + lrow] : 0.f;
#pragma unroll
            for (int s = 0; s < 2; ++s) {
                bf16x8 A[3];
#pragma unroll
                for (int kt = 0; kt < 3; ++kt)
                    A[kt] = *(const bf16x8*)&Xe[(s * 16 + lrow) * PXE + kt * 32 + lq * 8];
                floatx4 a0 = zero, a1 = zero;
#pragma unroll
                for (int kt = 0; kt < 3; ++kt) {
                    a0 = __builtin_amdgcn_mfma_f32_16x16x32_bf16(A[kt], F0[kt], a0, 0, 0, 0);
                    if (two)
                        a1 = __builtin_amdgcn_mfma_f32_16x16x32_bf16(A[kt], F1[kt], a1, 0, 0, 0);
                }
#pragma unroll
                for (int r_ = 0; r_ < 4; ++r_) {
                    int row = (s * 16 + lq * 4 + r_) * PXE;
                    LB[row + 16 * w4 + lrow] = f2b(fmaxf(a0[r_] + v0, 0.f));
                    if (two)
                        LB[row + 64 + 16 * w4 + lrow] = f2b(fmaxf(a1[r_] + v1, 0.f));
                }
            }
        }
        __syncthreads();   // B4: LB ready

        // le2: 96->32, wave w4 -> col-tile (w4&1), row-subtile (w4>>1); stores guarded rows < t
        {
            int ct = w4 & 1, s = w4 >> 1;
            int c0o = 16 * ct;
            bf16x8 F2[3];
#pragma unroll
            for (int kt = 0; kt < 3; ++kt)
                F2[kt] = *(const bf16x8*)(ple2 + (size_t)(c0o + lrow) * 96 + kt * 32 + lq * 8);
            float v2 = ble2[c0o + lrow];
            floatx4 a2 = zero;
#pragma unroll
            for (int kt = 0; kt < 3; ++kt) {
                bf16x8 a = *(const bf16x8*)&LB[(s * 16 + lrow) * PXE + kt * 32 + lq * 8];
                a2 = __builtin_amdgcn_mfma_f32_16x16x32_bf16(a, F2[kt], a2, 0, 0, 0);
            }
#pragma unroll
            for (int r_ = 0; r_ < 4; ++r_) {
                int grow = s * 16 + lq * 4 + r_;
                if (grow < t)
                    out_edges[(size_t)(base + grow) * 32 + c0o + lrow] = fmaxf(a2[r_] + v2, 0.f);
            }
        }
    }
}

// ---------------- final: node MLP ([pn|nodesb] 192->192->64) ----------------
__global__ __launch_bounds__(192) void k_final(
        const ushort_t* __restrict__ pn, const ushort_t* __restrict__ nodesb,
        const ushort_t* __restrict__ pln1, const float* __restrict__ bln1,
        const ushort_t* __restrict__ pln2, const float* __restrict__ bln2,
        float* __restrict__ out_nodes) {
    __shared__ alignas(16) ushort_t LA[32 * 200];
    __shared__ alignas(16) ushort_t LB[32 * 200];
    const int tid = threadIdx.x;
    const int w = tid >> 6, l = tid & 63, lrow = l & 15, lq = l >> 4;
    floatx4 zero = {0.f, 0.f, 0.f, 0.f};

    int tile = blockIdx.x;
    for (int u = tid; u < 768; u += 192) {        // 32 rows x 24 uint4 chunks
        int row = u / 24, c = u - row * 24;
        int r = tile * 32 + row;
        const uint4* src = (c < 16) ? ((const uint4*)(pn + (size_t)r * 128) + c)
                                    : ((const uint4*)(nodesb + (size_t)r * 64) + (c - 16));
        *(uint4*)&LA[row * 200 + c * 8] = *src;
    }
    bf16x8 f1[6][4]; float v1[4];
#pragma unroll
    for (int kt = 0; kt < 6; ++kt)
#pragma unroll
        for (int nt = 0; nt < 4; ++nt)
            f1[kt][nt] = *(const bf16x8*)(pln1 + (size_t)(w * 64 + nt * 16 + lrow) * 192 + kt * 32 + lq * 8);
#pragma unroll
    for (int nt = 0; nt < 4; ++nt) v1[nt] = bln1[w * 64 + nt * 16 + lrow];
    __syncthreads();

    floatx4 acc[2][4];
#pragma unroll
    for (int s = 0; s < 2; ++s)
#pragma unroll
        for (int nt = 0; nt < 4; ++nt) acc[s][nt] = zero;
#pragma unroll
    for (int s = 0; s < 2; ++s)
#pragma unroll
        for (int kt = 0; kt < 6; ++kt) {
            bf16x8 a = *(const bf16x8*)&LA[(s * 16 + lrow) * 200 + kt * 32 + lq * 8];
#pragma unroll
            for (int nt = 0; nt < 4; ++nt)
                acc[s][nt] = __builtin_amdgcn_mfma_f32_16x16x32_bf16(a, f1[kt][nt], acc[s][nt], 0, 0, 0);
        }
#pragma unroll
    for (int s = 0; s < 2; ++s)
#pragma unroll
        for (int nt = 0; nt < 4; ++nt) {
            int col = w * 64 + nt * 16 + lrow;
#pragma unroll
            for (int r_ = 0; r_ < 4; ++r_)
                LB[(s * 16 + lq * 4 + r_) * 200 + col] = f2b(fmaxf(acc[s][nt][r_] + v1[nt], 0.f));
        }
    bf16x8 f2[6][2]; float v2[2] = {0.f, 0.f};
    if (w < 2) {
#pragma unroll
        for (int kt = 0; kt < 6; ++kt)
#pragma unroll
            for (int nt = 0; nt < 2; ++nt)
                f2[kt][nt] = *(const bf16x8*)(pln2 + (size_t)(w * 32 + nt * 16 + lrow) * 192 + kt * 32 + lq * 8);
#pragma unroll
        for (int nt = 0; nt < 2; ++nt) v2[nt] = bln2[w * 32 + nt * 16 + lrow];
    }
    __syncthreads();
    if (w < 2) {
        floatx4 a2[2][2];
#pragma unroll
        for (int s = 0; s < 2; ++s) { a2[s][0] = zero; a2[s][1] = zero; }
#pragma unroll
        for (int s = 0; s < 2; ++s)
#pragma unroll
            for (int kt = 0; kt < 6; ++kt) {
                bf16x8 a = *(const bf16x8*)&LB[(s * 16 + lrow) * 200 + kt * 32 + lq * 8];
#pragma unroll
                for (int nt = 0; nt < 2; ++nt)
                    a2[s][nt] = __builtin_amdgcn_mfma_f32_16x16x32_bf16(a, f2[kt][nt], a2[s][nt], 0, 0, 0);
            }
#pragma unroll
        for (int s = 0; s < 2; ++s)
#pragma unroll
            for (int nt = 0; nt < 2; ++nt) {
                int col = w * 32 + nt * 16 + lrow;
#pragma unroll
                for (int r_ = 0; r_ < 4; ++r_)
                    out_nodes[(size_t)(tile * 32 + s * 16 + lq * 4 + r_) * 64 + col] =
                        fmaxf(a2[s][nt][r_] + v2[nt], 0.f);
            }
    }
}

extern "C" void kernel_launch(void* const* d_in, const int* in_sizes, int n_in,
                              void* d_out, int out_size, void* d_ws, size_t ws_size,
                              hipStream_t stream) {
    const float* nodes = (const float*)d_in[0];
    const float* edges = (const float*)d_in[1];
    const float* Wan1 = (const float*)d_in[2];  const float* ban1 = (const float*)d_in[3];
    const float* Wan2 = (const float*)d_in[4];  const float* ban2 = (const float*)d_in[5];
    const float* Wln1 = (const float*)d_in[6];  const float* bln1 = (const float*)d_in[7];
    const float* Wln2 = (const float*)d_in[8];  const float* bln2 = (const float*)d_in[9];
    const float* Wae1 = (const float*)d_in[10]; const float* bae1 = (const float*)d_in[11];
    const float* Wae2 = (const float*)d_in[12]; const float* bae2 = (const float*)d_in[13];
    const float* Wle1 = (const float*)d_in[14]; const float* ble1 = (const float*)d_in[15];
    const float* Wle2 = (const float*)d_in[16]; const float* ble2 = (const float*)d_in[17];

    char* ws = (char*)d_ws;
    size_t o = 0;
    auto alloc = [&](size_t bytes) -> void* {
        void* r = ws + o;
        o += (bytes + 255) & ~(size_t)255;
        return r;
    };
    ushort_t* pn     = (ushort_t*)alloc((size_t)2048 * 128 * 2);
    ushort_t* nodesb = (ushort_t*)alloc((size_t)2 * NN * 64 * 2);
    ushort_t* edgesb = (ushort_t*)alloc((size_t)MROWS * 32 * 2);
    ushort_t* pan1 = (ushort_t*)alloc(160 * 256 * 2);
    ushort_t* pan2 = (ushort_t*)alloc(256 * 128 * 2);
    ushort_t* pae1 = (ushort_t*)alloc(96 * 128 * 2);
    ushort_t* pae2 = (ushort_t*)alloc(128 * 64 * 2);
    ushort_t* ple1 = (ushort_t*)alloc(96 * 96 * 2);
    ushort_t* ple2 = (ushort_t*)alloc(96 * 32 * 2);
    ushort_t* pln1 = (ushort_t*)alloc(192 * 192 * 2);
    ushort_t* pln2 = (ushort_t*)alloc(192 * 64 * 2);

    float* out_nodes = (float*)d_out;
    float* out_edges = (float*)d_out + 2 * NN * 64;

    k_pack<<<2296, 256, 0, stream>>>(Wan1, Wan2, Wae1, Wae2, Wle1, Wle2, Wln1, Wln2,
                                     nodes, edges,
                                     pan1, pan2, pae1, pae2, ple1, ple2, pln1, pln2,
                                     nodesb, edgesb);
    k_main<<<3072, 512, 0, stream>>>(nodesb, edgesb,
                                     pan1, ban1, pan2, ban2,
                                     pae1, bae1, pae2, bae2,
                                     ple1, ble1, ple2, ble2,
                                     pn, out_edges);
    k_final<<<64, 192, 0, stream>>>(pn, nodesb, pln1, bln1, pln2, bln2, out_nodes);

    (void)in_sizes; (void)n_in; (void)out_size; (void)ws_size;
}